// Round 7
// baseline (19.825 us; speedup 1.0000x reference)
//
#include <hip/hip_runtime.h>

#define Bz    32
#define IN_C  32
#define OUT_C 128
#define HW    64

typedef float f32x4 __attribute__((ext_vector_type(4)));

// grid: Bz * OUT_C blocks of 256 threads, block index (oc major, b minor) so
// XCD = blk % 8 = b % 8  ->  each XCD serves 4 batches (2 MiB of x), L2-resident.
// Each block: one (b, oc). Each thread: 4 rows x 4 consecutive w.
// Phase 1: issue ALL 12 float4 loads into a live array (max MLP),
// Phase 2: shuffles + max, Phase 3: 4 plain f32x4 stores (L2 write-combining;
// R1 evidence: streaming out through L2 does NOT evict x).
__global__ __launch_bounds__(256) void dist_conv2d_kernel(
    const float* __restrict__ x,       // [B, IN_C, 64, 64]
    const float* __restrict__ weights, // [OUT_C, 3]
    const float* __restrict__ bias,    // [OUT_C]
    const int*   __restrict__ conn,    // [OUT_C*3]
    float*       __restrict__ out)     // [B, OUT_C, 64, 64]
{
    const int blk = blockIdx.x;
    const int b   = blk & (Bz - 1);    // minor: batch
    const int oc  = blk >> 5;          // major: out-channel

    const int tid = threadIdx.x;
    const int wq  = tid & 15;          // 16 quads cover W=64
    const int hr  = tid >> 4;          // 0..15
    const int w0  = wq * 4;

    // block-uniform per-oc parameters, forced scalar
    float wgt[3];
    int   cch[3], di[3], dj[3];
#pragma unroll
    for (int k = 0; k < 3; ++k) {
        int cidx = __builtin_amdgcn_readfirstlane(conn[oc * 3 + k]);
        int c    = cidx / 9;
        int r    = cidx - c * 9;
        int i    = r / 3;
        int j    = r - i * 3;
        cch[k] = c;
        di[k]  = i - 1;   // replicate pad of 1
        dj[k]  = j - 1;
        wgt[k] = weights[oc * 3 + k];
    }
    const float bs = bias[oc];
    const float* __restrict__ xb = x + (size_t)b * IN_C * HW * HW;

    // ---- Phase 1: issue all 12 loads ----
    f32x4 v[3][4];  // [k][rr]
#pragma unroll
    for (int k = 0; k < 3; ++k) {
        const float* __restrict__ plane = xb + (size_t)cch[k] * HW * HW;
#pragma unroll
        for (int rr = 0; rr < 4; ++rr) {
            int hh = hr + 16 * rr + di[k];
            hh = hh < 0 ? 0 : (hh > HW - 1 ? HW - 1 : hh);
            v[k][rr] = *reinterpret_cast<const f32x4*>(plane + hh * HW + w0);
        }
    }

    // ---- Phase 2: shuffle + max ----
    f32x4 res[4];
#pragma unroll
    for (int rr = 0; rr < 4; ++rr) {
        float d0 = 0.f, d1 = 0.f, d2 = 0.f, d3 = 0.f;
#pragma unroll
        for (int k = 0; k < 3; ++k) {
            f32x4 vv = v[k][rr];
            float a, e, f, g;
            if (dj[k] == 0) {
                a = vv.x; e = vv.y; f = vv.z; g = vv.w;
            } else if (dj[k] > 0) {           // need w0+1 .. w0+4 (clamp 63)
                float nx = __shfl_down(vv.x, 1, 16);
                a = vv.y; e = vv.z; f = vv.w;
                g = (wq == 15) ? vv.w : nx;
            } else {                          // need w0-1 .. w0+2 (clamp 0)
                float pw = __shfl_up(vv.w, 1, 16);
                a = (wq == 0) ? vv.x : pw;
                e = vv.x; f = vv.y; g = vv.z;
            }
            const float wk = wgt[k];
            d0 = fmaxf(d0, fabsf(wk - a));
            d1 = fmaxf(d1, fabsf(wk - e));
            d2 = fmaxf(d2, fabsf(wk - f));
            d3 = fmaxf(d3, fabsf(wk - g));
        }
        f32x4 r4; r4.x = d0 + bs; r4.y = d1 + bs; r4.z = d2 + bs; r4.w = d3 + bs;
        res[rr] = r4;
    }

    // ---- Phase 3: plain stores ----
#pragma unroll
    for (int rr = 0; rr < 4; ++rr) {
        const int h = hr + 16 * rr;
        *reinterpret_cast<f32x4*>(out + ((size_t)(b * OUT_C + oc) * HW + h) * HW + w0) = res[rr];
    }
}

extern "C" void kernel_launch(void* const* d_in, const int* in_sizes, int n_in,
                              void* d_out, int out_size, void* d_ws, size_t ws_size,
                              hipStream_t stream) {
    const float* x       = (const float*)d_in[0];
    const float* weights = (const float*)d_in[1];
    const float* bias    = (const float*)d_in[2];
    const int*   conn    = (const int*)d_in[3];
    float*       out     = (float*)d_out;

    const int grid = Bz * OUT_C;  // 4096 blocks
    dist_conv2d_kernel<<<grid, 256, 0, stream>>>(x, weights, bias, conn, out);
}

// Round 8
// 17.714 us; speedup vs baseline: 1.1192x; 1.1192x over previous
//
#include <hip/hip_runtime.h>

#define Bz    32
#define IN_C  32
#define OUT_C 128
#define HW    64

typedef float f32x4 __attribute__((ext_vector_type(4)));

// grid: Bz * OUT_C blocks of 256 threads, block index (oc major, b minor) so
// XCD = blk % 8 = b % 8  ->  each XCD serves 4 batches (2 MiB of x), L2-resident.
// Each block: one (b, oc). Each thread: 4 rows x 4 consecutive w.
// Loads issued ROW-major so row rr is complete after 3(rr+1) load returns;
// each row is computed + NT-stored as soon as its 3 operands land, overlapping
// store issue with outstanding load returns (R7 showed NT stores are +10%).
__global__ __launch_bounds__(256) void dist_conv2d_kernel(
    const float* __restrict__ x,       // [B, IN_C, 64, 64]
    const float* __restrict__ weights, // [OUT_C, 3]
    const float* __restrict__ bias,    // [OUT_C]
    const int*   __restrict__ conn,    // [OUT_C*3]
    float*       __restrict__ out)     // [B, OUT_C, 64, 64]
{
    const int blk = blockIdx.x;
    const int b   = blk & (Bz - 1);    // minor: batch
    const int oc  = blk >> 5;          // major: out-channel

    const int tid = threadIdx.x;
    const int wq  = tid & 15;          // 16 quads cover W=64
    const int hr  = tid >> 4;          // 0..15
    const int w0  = wq * 4;

    // block-uniform per-oc parameters, forced scalar
    float wgt[3];
    int   cch[3], di[3], dj[3];
#pragma unroll
    for (int k = 0; k < 3; ++k) {
        int cidx = __builtin_amdgcn_readfirstlane(conn[oc * 3 + k]);
        int c    = cidx / 9;
        int r    = cidx - c * 9;
        int i    = r / 3;
        int j    = r - i * 3;
        cch[k] = c;
        di[k]  = i - 1;   // replicate pad of 1
        dj[k]  = j - 1;
        wgt[k] = weights[oc * 3 + k];
    }
    const float bs = bias[oc];
    const float* __restrict__ xb = x + (size_t)b * IN_C * HW * HW;
    float* __restrict__ ob = out + ((size_t)(b * OUT_C + oc)) * HW * HW;

    // ---- Phase 1: issue all 12 loads, ROW-major ----
    f32x4 v[4][3];  // [rr][k]
#pragma unroll
    for (int rr = 0; rr < 4; ++rr) {
#pragma unroll
        for (int k = 0; k < 3; ++k) {
            int hh = hr + 16 * rr + di[k];
            hh = hh < 0 ? 0 : (hh > HW - 1 ? HW - 1 : hh);
            v[rr][k] = *reinterpret_cast<const f32x4*>(xb + ((size_t)cch[k] * HW + hh) * HW + w0);
        }
    }

    // ---- Phase 2: per-row shuffle + max + immediate NT store ----
#pragma unroll
    for (int rr = 0; rr < 4; ++rr) {
        float d0 = 0.f, d1 = 0.f, d2 = 0.f, d3 = 0.f;
#pragma unroll
        for (int k = 0; k < 3; ++k) {
            f32x4 vv = v[rr][k];
            float a, e, f, g;
            if (dj[k] == 0) {
                a = vv.x; e = vv.y; f = vv.z; g = vv.w;
            } else if (dj[k] > 0) {           // need w0+1 .. w0+4 (clamp 63)
                float nx = __shfl_down(vv.x, 1, 16);
                a = vv.y; e = vv.z; f = vv.w;
                g = (wq == 15) ? vv.w : nx;
            } else {                          // need w0-1 .. w0+2 (clamp 0)
                float pw = __shfl_up(vv.w, 1, 16);
                a = (wq == 0) ? vv.x : pw;
                e = vv.x; f = vv.y; g = vv.z;
            }
            const float wk = wgt[k];
            d0 = fmaxf(d0, fabsf(wk - a));
            d1 = fmaxf(d1, fabsf(wk - e));
            d2 = fmaxf(d2, fabsf(wk - f));
            d3 = fmaxf(d3, fabsf(wk - g));
        }
        f32x4 r4; r4.x = d0 + bs; r4.y = d1 + bs; r4.z = d2 + bs; r4.w = d3 + bs;
        const int h = hr + 16 * rr;
        __builtin_nontemporal_store(r4, reinterpret_cast<f32x4*>(ob + h * HW + w0));
    }
}

extern "C" void kernel_launch(void* const* d_in, const int* in_sizes, int n_in,
                              void* d_out, int out_size, void* d_ws, size_t ws_size,
                              hipStream_t stream) {
    const float* x       = (const float*)d_in[0];
    const float* weights = (const float*)d_in[1];
    const float* bias    = (const float*)d_in[2];
    const int*   conn    = (const int*)d_in[3];
    float*       out     = (float*)d_out;

    const int grid = Bz * OUT_C;  // 4096 blocks
    dist_conv2d_kernel<<<grid, 256, 0, stream>>>(x, weights, bias, conn, out);
}